// Round 22
// baseline (209.353 us; speedup 1.0000x reference)
//
#include <hip/hip_runtime.h>

// GPT forward, MI355X gfx950. bf16 MFMA, fused MLP (no activation), max-free
// exp2-softmax (Q pre-scaled log2(e)/8 in weights), KV-split (4-tile chunks)
// XCD-pinned attn @4 blocks/CU, bf16 O-partials, bf16 residual stream,
// fused layer megakernel (early weight-stage issue), bf16 head GEMM with
// LDS-transposed coalesced epilogue. All scratch in d_ws.
// B=4,T=2048,C=256,H=4,D=64,L=4.

typedef __attribute__((ext_vector_type(8))) short short8;
typedef __attribute__((ext_vector_type(4))) short short4_t;
typedef __attribute__((ext_vector_type(4))) float f32x4;

#define QSCALE 0.18033688011112042f   // log2(e)/8 : softmax computed as exp2

static __device__ __forceinline__ short f2bf(float f) {
    unsigned int u = __float_as_uint(f);
    unsigned int r = (u + 0x7FFFu + ((u >> 16) & 1u)) >> 16;  // RNE
    return (short)r;
}
static __device__ __forceinline__ float bf2f(short s) {
    return __uint_as_float(((unsigned)(unsigned short)s) << 16);
}

static __device__ __forceinline__ void glds16(const void* g, void* l) {
    __builtin_amdgcn_global_load_lds(
        (const __attribute__((address_space(1))) unsigned int*)g,
        (__attribute__((address_space(3))) unsigned int*)l, 16, 0, 0);
}

// ---------------- consolidated prep + embed ----------------------------------
__global__ __launch_bounds__(256) void prep_kernel(
    const float* __restrict__ Wqkv, const float* __restrict__ Wo,
    const float* __restrict__ Wfc, const float* __restrict__ Wfp,
    const float* __restrict__ Whead, const float* __restrict__ bfc,
    const float* __restrict__ bqkv,
    const int* __restrict__ idx, const float* __restrict__ tok,
    const float* __restrict__ pos,
    short* __restrict__ wqkv_t, short* __restrict__ wo_t,
    short* __restrict__ whead_t,
    float* __restrict__ wmlp_part, float* __restrict__ bmlp_part,
    float* __restrict__ bq_s, short* __restrict__ xb) {
    int b = blockIdx.x;
    if (b >= 1860) {
        int i = ((b - 1860) * 256 + threadIdx.x) * 4;
        int row = i >> 8, c = i & 255, t = row & 2047;
        int tr = idx[row];
        float4 a = *(const float4*)(tok + (size_t)tr * 256 + c);
        float4 p = *(const float4*)(pos + (size_t)t * 256 + c);
        short4_t s;
        s.x = f2bf(a.x + p.x); s.y = f2bf(a.y + p.y);
        s.z = f2bf(a.z + p.z); s.w = f2bf(a.w + p.w);
        *(short4_t*)(xb + i) = s;
        return;
    }
    if (b < 1536) {
        __shared__ float tile[32][33];
        const float* src; short* dst; int R, C, c0, r0; bool qs = false;
        if (b < 768)       { int l = b / 192, r = b % 192;
            src = Wqkv + (size_t)l * 196608; dst = wqkv_t + (size_t)l * 196608;
            R = 256; C = 768; c0 = (r % 24) * 32; r0 = (r / 24) * 32; qs = true; }
        else if (b < 1024) { int t = b - 768; int l = t >> 6, r = t & 63;
            src = Wo + (size_t)l * 65536; dst = wo_t + (size_t)l * 65536;
            R = 256; C = 256; c0 = (r & 7) * 32; r0 = (r >> 3) * 32; }
        else               { int t = b - 1024;
            src = Whead; dst = whead_t;
            R = 256; C = 2048; c0 = (t & 63) * 32; r0 = (t >> 6) * 32; }
        int tx = threadIdx.x & 31, ty = threadIdx.x >> 5;
        #pragma unroll
        for (int i = 0; i < 4; ++i)
            tile[ty + 8 * i][tx] = src[(size_t)(r0 + ty + 8 * i) * C + c0 + tx];
        __syncthreads();
        #pragma unroll
        for (int i = 0; i < 4; ++i) {
            int n = c0 + ty + 8 * i;
            float v = tile[tx][ty + 8 * i];
            if (qs && n < 256) v *= QSCALE;
            dst[(size_t)n * R + r0 + tx] = f2bf(v);
        }
    } else if (b < 1792) {
        __shared__ short As[2][64][40];
        __shared__ short Bs[2][64][40];
        int t = b - 1536, l = t >> 6, r = (t >> 2) & 15, kc = t & 3;
        const float* A = Wfc + (size_t)l * 262144;
        const float* W = Wfp + (size_t)l * 262144;
        int m0 = (r >> 2) * 64, n0 = (r & 3) * 64, kb = kc * 256;
        int tid = threadIdx.x, lane = tid & 63, wid = tid >> 6;
        int lg = lane >> 4, lr = lane & 15;
        int wm = (wid >> 1) * 32, wn = (wid & 1) * 32;
        f32x4 acc[2][2] = {};
        float4 pa0, pa1; float pb[8];
        int ar = tid >> 3, ac4 = (tid & 7) * 4;
        int bn = tid & 63, bk8 = (tid >> 6) * 8;
        auto gload = [&](int k0) {
            pa0 = *(const float4*)(A + (size_t)(m0 + ar) * 1024 + k0 + ac4);
            pa1 = *(const float4*)(A + (size_t)(m0 + ar + 32) * 1024 + k0 + ac4);
            #pragma unroll
            for (int j = 0; j < 8; ++j) pb[j] = W[(size_t)(k0 + bk8 + j) * 256 + n0 + bn];
        };
        auto sstore = [&](int buf) {
            short4_t s0; s0.x=f2bf(pa0.x); s0.y=f2bf(pa0.y); s0.z=f2bf(pa0.z); s0.w=f2bf(pa0.w);
            *(short4_t*)&As[buf][ar][ac4] = s0;
            short4_t s1; s1.x=f2bf(pa1.x); s1.y=f2bf(pa1.y); s1.z=f2bf(pa1.z); s1.w=f2bf(pa1.w);
            *(short4_t*)&As[buf][ar + 32][ac4] = s1;
            short8 bb;
            #pragma unroll
            for (int j = 0; j < 8; ++j) bb[j] = f2bf(pb[j]);
            *(short8*)&Bs[buf][bn][bk8] = bb;
        };
        gload(kb); sstore(0); __syncthreads();
        for (int tt = 0; tt < 8; ++tt) {
            if (tt + 1 < 8) gload(kb + ((tt + 1) << 5));
            int cur = tt & 1;
            short8 af[2], bfr[2];
            af[0]  = *(const short8*)&As[cur][wm + lr][lg * 8];
            af[1]  = *(const short8*)&As[cur][wm + 16 + lr][lg * 8];
            bfr[0] = *(const short8*)&Bs[cur][wn + lr][lg * 8];
            bfr[1] = *(const short8*)&Bs[cur][wn + 16 + lr][lg * 8];
            #pragma unroll
            for (int mi = 0; mi < 2; ++mi)
                #pragma unroll
                for (int ni = 0; ni < 2; ++ni)
                    acc[mi][ni] = __builtin_amdgcn_mfma_f32_16x16x32_bf16(
                        af[mi], bfr[ni], acc[mi][ni], 0, 0, 0);
            if (tt + 1 < 8) sstore((tt + 1) & 1);
            __syncthreads();
        }
        float* part = wmlp_part + (size_t)t * 4096;
        #pragma unroll
        for (int mi = 0; mi < 2; ++mi)
            #pragma unroll
            for (int ni = 0; ni < 2; ++ni) {
                int col = wn + ni * 16 + lr;
                #pragma unroll
                for (int rr = 0; rr < 4; ++rr) {
                    int row = wm + mi * 16 + lg * 4 + rr;
                    part[row * 64 + col] = acc[mi][ni][rr];
                }
            }
    } else if (b < 1856) {
        int t = b - 1792, l = t >> 4, kc = t & 15;
        int n = threadIdx.x;
        const float* w = Wfp + (size_t)l * 262144 + n;
        const float* bf = bfc + l * 1024;
        float s = 0.0f;
        #pragma unroll 8
        for (int k = kc * 64; k < kc * 64 + 64; ++k)
            s += bf[k] * w[(size_t)k * 256];
        bmlp_part[t * 256 + n] = s;
    } else {
        int l = b - 1856;
        for (int k = threadIdx.x; k < 768; k += 256)
            bq_s[l * 768 + k] = bqkv[l * 768 + k] * (k < 256 ? QSCALE : 1.0f);
    }
}

// ---------------- bf16 GEMM core (3-buf glds pipeline) -----------------------
// MODE 0: fp32 out via LDS-transposed coalesced epilogue (head).
// MODE 1: qkv split epilogue + piggybacked combine at blockIdx.y >= 128.
template<int MODE>
__global__ __launch_bounds__(256) void gemmb_kernel(
    const short* __restrict__ A, const short* __restrict__ Bt,
    const float* __restrict__ bias, float* __restrict__ outf,
    short* __restrict__ qg, short* __restrict__ kg, short* __restrict__ vg,
    const float* __restrict__ wmlp_part, const float* __restrict__ bmlp_part,
    const float* __restrict__ bfp,
    short* __restrict__ wmlp_t, float* __restrict__ bmlp,
    int N, int K) {
    if constexpr (MODE == 1) {
        if (blockIdx.y >= 128) {          // piggybacked combine blocks
            int t = (blockIdx.y - 128) * 12 + blockIdx.x;
            if (t >= 68) return;
            if (t < 64) {
                int l = t >> 4, r = t & 15;
                int m0 = (r >> 2) * 64, n0 = (r & 3) * 64;
                int slab0 = t * 4;
                int rc = threadIdx.x >> 6, nl = threadIdx.x & 63;
                #pragma unroll
                for (int rr = 0; rr < 16; ++rr) {
                    int row = rc * 16 + rr;
                    float s = wmlp_part[(size_t)(slab0 + 0) * 4096 + row * 64 + nl]
                            + wmlp_part[(size_t)(slab0 + 1) * 4096 + row * 64 + nl]
                            + wmlp_part[(size_t)(slab0 + 2) * 4096 + row * 64 + nl]
                            + wmlp_part[(size_t)(slab0 + 3) * 4096 + row * 64 + nl];
                    wmlp_t[(size_t)l * 65536 + (size_t)(n0 + nl) * 256 + m0 + row] = f2bf(s);
                }
            } else {
                int l = t - 64, n = threadIdx.x;
                float s = bfp[l * 256 + n];
                #pragma unroll
                for (int kc = 0; kc < 16; ++kc)
                    s += bmlp_part[(l * 16 + kc) * 256 + n];
                bmlp[l * 256 + n] = s;
            }
            return;
        }
    }
    __shared__ short Asb[3][4096];
    __shared__ short Bsb[3][4096];
    int tid = threadIdx.x, lane = tid & 63, wid = tid >> 6;
    int lg = lane >> 4, lr = lane & 15;
    int m0 = blockIdx.y * 64, n0 = blockIdx.x * 64;
    int wm = (wid >> 1) * 32, wn = (wid & 1) * 32;
    int srow = lane >> 3;
    int gc = (lane & 7) ^ (srow & 7);
    int nt = K >> 6;

    auto stage = [&](int t) {
        int buf = t - (t / 3) * 3;
        int k0 = t << 6;
        #pragma unroll
        for (int o2 = 0; o2 < 2; ++o2) {
            int o = wid * 2 + o2;
            glds16(A + (size_t)(m0 + o * 8 + srow) * K + k0 + gc * 8, &Asb[buf][o * 512]);
            glds16(Bt + (size_t)(n0 + o * 8 + srow) * K + k0 + gc * 8, &Bsb[buf][o * 512]);
        }
    };

    f32x4 acc[2][2] = {};
    stage(0);
    if (nt > 1) stage(1);

    for (int t = 0; t < nt; ++t) {
        if (t + 1 < nt) asm volatile("s_waitcnt vmcnt(4)" ::: "memory");
        else            asm volatile("s_waitcnt vmcnt(0)" ::: "memory");
        __builtin_amdgcn_s_barrier();
        if (t + 2 < nt) stage(t + 2);
        int buf = t - (t / 3) * 3;
        short8 af[2][2], bfr[2][2];
        #pragma unroll
        for (int mi = 0; mi < 2; ++mi) {
            int row = wm + mi * 16 + lr;
            #pragma unroll
            for (int h = 0; h < 2; ++h)
                af[mi][h] = *(const short8*)&Asb[buf][row * 64 + ((h * 4 + lg) ^ (lr & 7)) * 8];
        }
        #pragma unroll
        for (int ni = 0; ni < 2; ++ni) {
            int row = wn + ni * 16 + lr;
            #pragma unroll
            for (int h = 0; h < 2; ++h)
                bfr[ni][h] = *(const short8*)&Bsb[buf][row * 64 + ((h * 4 + lg) ^ (lr & 7)) * 8];
        }
        #pragma unroll
        for (int h = 0; h < 2; ++h)
            #pragma unroll
            for (int mi = 0; mi < 2; ++mi)
                #pragma unroll
                for (int ni = 0; ni < 2; ++ni)
                    acc[mi][ni] = __builtin_amdgcn_mfma_f32_16x16x32_bf16(
                        af[mi][h], bfr[ni][h], acc[mi][ni], 0, 0, 0);
    }

    if constexpr (MODE == 0) {
        // LDS-transposed epilogue: coalesced 256B row segments.
        __syncthreads();                       // staging buffers now dead
        float* ot = (float*)&Asb[0][0];        // 24 KB >= 64*68*4 B
        #pragma unroll
        for (int mi = 0; mi < 2; ++mi)
            #pragma unroll
            for (int ni = 0; ni < 2; ++ni)
                #pragma unroll
                for (int r = 0; r < 4; ++r)
                    ot[(wm + mi * 16 + lg * 4 + r) * 68 + wn + ni * 16 + lr]
                        = acc[mi][ni][r];
        __syncthreads();
        #pragma unroll
        for (int pass = 0; pass < 4; ++pass) {
            int row = pass * 16 + (tid >> 4);
            int col = (tid & 15) * 4;
            f32x4 v = *(const f32x4*)&ot[row * 68 + col];
            __builtin_nontemporal_store(v,
                (f32x4*)&outf[(size_t)(m0 + row) * N + n0 + col]);
        }
    } else {
        #pragma unroll
        for (int mi = 0; mi < 2; ++mi) {
            #pragma unroll
            for (int ni = 0; ni < 2; ++ni) {
                int col = n0 + wn + ni * 16 + lr;
                float bv = bias[col];
                int sec = col >> 8, h = (col >> 6) & 3, d = col & 63;
                int rb = m0 + wm + mi * 16 + lg * 4;
                int t2 = rb & 2047, bh = ((rb >> 11) << 2) | h;
                if (sec == 2) {
                    short4_t pk;
                    #pragma unroll
                    for (int r = 0; r < 4; ++r) pk[r] = f2bf(acc[mi][ni][r] + bv);
                    *(short4_t*)&vg[(size_t)bh * 131072 + (size_t)d * 2048 + t2] = pk;
                } else {
                    short* dst = (sec == 0 ? qg : kg) + (size_t)bh * 131072 + (size_t)t2 * 64 + d;
                    #pragma unroll
                    for (int r = 0; r < 4; ++r) dst[r * 64] = f2bf(acc[mi][ni][r] + bv);
                }
            }
        }
    }
}

// ---------------- causal flash attention, 4-tile chunks, XCD-pinned ----------
// Ps unpadded [4][16][64] with chunk-XOR swizzle -> 40960 B LDS -> 4 blocks/CU.
// stage(t0) issued before Q-frag loads so Q latency overlaps first K/V stage.
__global__ __launch_bounds__(256, 4) void attn_kernel(
    const short* __restrict__ qg, const short* __restrict__ kg,
    const short* __restrict__ vg, short* __restrict__ Opb, float* __restrict__ rp) {
    __shared__ short Kb[2][4096];
    __shared__ short Vb[2][4096];
    __shared__ short Ps[4][16][64];
    int g = blockIdx.x;
    int idx = g >> 3;
    int bh = (g & 7) * 2 + (idx / 144);
    int i = 143 - (idx % 144);          // heavy chunks first
    int g4 = 0;
    #pragma unroll
    for (int t = 7; t >= 1; --t) if (i >= 2 * t * (t + 1)) { g4 = t; break; }
    int j0 = i - 2 * g4 * (g4 + 1);
    int qq = j0 / (g4 + 1);
    int qt = g4 * 4 + qq;
    int s = j0 - qq * (g4 + 1);
    int t0 = s * 4;
    int t1 = min(t0 + 4, qt + 1);
    int q0 = qt << 6;
    int tid = threadIdx.x, lane = tid & 63, wid = tid >> 6;
    int lg = lane >> 4, lr = lane & 15;
    const size_t base = (size_t)bh << 17;
    int srow = lane >> 3;
    int gc = (lane & 7) ^ (srow & 7);

    auto stage = [&](int t) {
        int buf = (t - t0) & 1;
        #pragma unroll
        for (int o2 = 0; o2 < 2; ++o2) {
            int o = wid * 2 + o2;
            glds16(kg + base + (size_t)(t * 64 + o * 8 + srow) * 64 + gc * 8, &Kb[buf][o * 512]);
            glds16(vg + base + (size_t)(o * 8 + srow) * 2048 + t * 64 + gc * 8, &Vb[buf][o * 512]);
        }
    };

    stage(t0);                                // K/V stage first ...
    const short* qrow = qg + base + (size_t)(q0 + wid * 16 + lr) * 64;
    short8 qf0 = *(const short8*)(qrow + lg * 8);      // ... Q overlaps it
    short8 qf1 = *(const short8*)(qrow + 32 + lg * 8);

    f32x4 o[4] = {};
    float rs = 0.0f;

    for (int j = t0; j < t1; ++j) {
        if (j + 1 < t1) {
            stage(j + 1);
            asm volatile("s_waitcnt vmcnt(4)" ::: "memory");
        } else {
            asm volatile("s_waitcnt vmcnt(0)" ::: "memory");
        }
        __builtin_amdgcn_s_barrier();
        int buf = (j - t0) & 1;

        f32x4 sv[4];
        #pragma unroll
        for (int nf = 0; nf < 4; ++nf) {
            int row = nf * 16 + lr;
            short8 k0f = *(const short8*)&Kb[buf][row * 64 + ((0 + lg) ^ (lr & 7)) * 8];
            short8 k1f = *(const short8*)&Kb[buf][row * 64 + ((4 + lg) ^ (lr & 7)) * 8];
            f32x4 z = {};
            z = __builtin_amdgcn_mfma_f32_16x16x32_bf16(k0f, qf0, z, 0, 0, 0);
            z = __builtin_amdgcn_mfma_f32_16x16x32_bf16(k1f, qf1, z, 0, 0, 0);
            sv[nf] = z;
        }
        bool diagt = (j == qt);
        #pragma unroll
        for (int nf = 0; nf < 4; ++nf) {
            float pe[4];
            if (diagt) {
                #pragma unroll
                for (int r = 0; r < 4; ++r) {
                    float v = sv[nf][r];
                    if (nf * 16 + lg * 4 + r > wid * 16 + lr) v = -3e38f;
                    asm("v_exp_f32 %0, %1" : "=v"(pe[r]) : "v"(v));
                }
            } else {
                #pragma unroll
                for (int r = 0; r < 4; ++r)
                    asm("v_exp_f32 %0, %1" : "=v"(pe[r]) : "v"(sv[nf][r]));
            }
            rs += (pe[0] + pe[1]) + (pe[2] + pe[3]);
            unsigned r01, r23;
            asm("v_cvt_pk_bf16_f32 %0, %1, %2" : "=v"(r01) : "v"(pe[0]), "v"(pe[1]));
            asm("v_cvt_pk_bf16_f32 %0, %1, %2" : "=v"(r23) : "v"(pe[2]), "v"(pe[3]));
            uint2 u2; u2.x = r01; u2.y = r23;
            *(uint2*)&Ps[wid][lr][((nf * 2 + (lg >> 1)) ^ (lr & 7)) * 8 + (lg & 1) * 4] = u2;
        }
        short8 pf0 = *(const short8*)&Ps[wid][lr][((lg) ^ (lr & 7)) * 8];
        short8 pf1 = *(const short8*)&Ps[wid][lr][((4 + lg) ^ (lr & 7)) * 8];
        #pragma unroll
        for (int df = 0; df < 4; ++df) {
            int row = df * 16 + lr;
            short8 v0 = *(const short8*)&Vb[buf][row * 64 + ((0 + lg) ^ (lr & 7)) * 8];
            short8 v1 = *(const short8*)&Vb[buf][row * 64 + ((4 + lg) ^ (lr & 7)) * 8];
            o[df] = __builtin_amdgcn_mfma_f32_16x16x32_bf16(pf0, v0, o[df], 0, 0, 0);
            o[df] = __builtin_amdgcn_mfma_f32_16x16x32_bf16(pf1, v1, o[df], 0, 0, 0);
        }
        __builtin_amdgcn_s_barrier();
    }

    rs += __shfl_xor(rs, 16);
    rs += __shfl_xor(rs, 32);

    int slab = ((bh * 32 + qt) << 3) + s;
    short* ob = Opb + (size_t)slab * 4096;
    #pragma unroll
    for (int df = 0; df < 4; ++df)
        #pragma unroll
        for (int r = 0; r < 4; ++r)
            __builtin_nontemporal_store(f2bf(o[df][r]),
                ob + (wid * 16 + lg * 4 + r) * 64 + df * 16 + lr);
    if (lane < 16) rp[slab * 64 + wid * 16 + lane] = rs;
}

// ---------------- fused layer: combine+proj+MLP+next-qkv ---------------------
// bf16 residual stream xg. Weight stages 0/1 issued BEFORE combine (overlap);
// stage(s+2) issued before store_a (overlaps al write + barrier).
// XCD-pinned: block bid -> xcd=bid&7 serves batch b=xcd>>1 (matches attn pin).
__global__ __launch_bounds__(512) void layer_kernel(
    const short* __restrict__ Opb, const float* __restrict__ rp,
    short* __restrict__ xg,
    const short* __restrict__ wo, const float* __restrict__ bo,
    const short* __restrict__ wmlp, const float* __restrict__ bmlp,
    const short* __restrict__ wqkv, const float* __restrict__ bqkv,
    short* __restrict__ qg, short* __restrict__ kg, short* __restrict__ vg) {
    __shared__ short al[4][32][64];      // 16 KB (A operand, swizzled)
    __shared__ short wl[2][32768];       // 2 x 64 KB (weight half-K buffers)
    int tid = threadIdx.x, lane = tid & 63, wid = tid >> 6;
    int lg = (lane >> 4) & 3, lr = lane & 15;
    int bid = blockIdx.x;
    int xcd = bid & 7, slot = bid >> 3;
    int b = xcd >> 1;
    int r0 = (b * 64 + slot * 2 + (xcd & 1)) * 32;
    int qt = (r0 & 2047) >> 6;
    int rowIn0 = r0 & 32;
    int ns = (qt >> 2) + 1;
    int wr = (wid & 1) * 16, wc = (wid >> 1) * 64;
    bool last = (wqkv == nullptr);

    const short* wlist[5];
    wlist[0] = wo; wlist[1] = wmlp;
    wlist[2] = last ? wo : wqkv;
    wlist[3] = last ? wo : wqkv + 65536;
    wlist[4] = last ? wo : wqkv + 131072;
    int nsteps = last ? 4 : 10;

    auto stage_w = [&](int s) {
        const short* wt = wlist[s >> 1];
        int h = s & 1;
        short* dst = wl[h];
        int n_l = lane >> 4, cl = lane & 15;
        #pragma unroll
        for (int c4 = 0; c4 < 8; ++c4) {
            int n0 = wid * 32 + c4 * 4;
            int n = n0 + n_l;
            glds16(wt + (size_t)n * 256 + h * 128 + (cl ^ (n & 15)) * 8,
                   dst + n0 * 128);
        }
    };
    auto store_a = [&](f32x4* v) {
        #pragma unroll
        for (int f = 0; f < 4; ++f) {
            int col = wc + f * 16 + lr;
            int h2 = col >> 6, ch = (col & 63) >> 3, pos = col & 7;
            #pragma unroll
            for (int rr = 0; rr < 4; ++rr) {
                int row = wr + lg * 4 + rr;
                al[h2][row][(ch ^ (row & 7)) * 8 + pos] = f2bf(v[f][rr]);
            }
        }
    };

    stage_w(0);                          // weight stages fly during combine
    stage_w(1);

    // ---- combine bf16 partials -> y bf16 in al ----
    {
        int row = tid >> 4, seg = tid & 15;
        int h = seg >> 2, d0 = (seg & 3) * 16;
        int slab0 = (((b * 4 + h) * 32 + qt) << 3);
        float a[16] = {};
        float rtot = 0.0f;
        for (int s = 0; s < ns; ++s) {
            const short* op = Opb + (size_t)(slab0 + s) * 4096 + (rowIn0 + row) * 64 + d0;
            #pragma unroll
            for (int i2 = 0; i2 < 4; ++i2) {
                short4_t v = *(const short4_t*)(op + i2 * 4);
                a[i2*4+0] += bf2f(v.x); a[i2*4+1] += bf2f(v.y);
                a[i2*4+2] += bf2f(v.z); a[i2*4+3] += bf2f(v.w);
            }
            rtot += rp[(slab0 + s) * 64 + rowIn0 + row];
        }
        float inv = 1.0f / rtot;
        short8 o0, o1;
        #pragma unroll
        for (int i2 = 0; i2 < 8; ++i2) { o0[i2] = f2bf(a[i2] * inv); o1[i2] = f2bf(a[8 + i2] * inv); }
        int c0 = d0 >> 3;
        *(short8*)&al[h][row][((c0) ^ (row & 7)) * 8] = o0;
        *(short8*)&al[h][row][((c0 + 1) ^ (row & 7)) * 8] = o1;
    }

    asm volatile("s_waitcnt lgkmcnt(0)" ::: "memory");   // al writes visible
    __builtin_amdgcn_s_barrier();

    f32x4 acc[4] = {};
    f32x4 x1[4], x2[4];

    for (int s = 0; s < nsteps; ++s) {
        if (s == nsteps - 1) asm volatile("s_waitcnt vmcnt(0)" ::: "memory");
        else                 asm volatile("s_waitcnt vmcnt(8)" ::: "memory");
        __builtin_amdgcn_s_barrier();
        int h = s & 1, p = s >> 1;
        const short* wb = wl[h];
        #pragma unroll
        for (int s2 = 0; s2 < 4; ++s2) {
            int ksg = h * 4 + s2;
            short8 a = *(const short8*)&al[ksg >> 1][wr + lr][((((ksg & 1) << 2) + lg) ^ (lr & 7)) * 8];
            #pragma unroll
            for (int f = 0; f < 4; ++f) {
                int n = wc + f * 16 + lr;
                short8 bf8 = *(const short8*)&wb[n * 128 + (((s2 * 4 + lg) ^ lr) * 8)];
                acc[f] = __builtin_amdgcn_mfma_f32_16x16x32_bf16(a, bf8, acc[f], 0, 0, 0);
            }
        }
        bool phase_end = (h == 1);
        bool need_store = false;
        if (phase_end) {
            if (p == 0) {
                #pragma unroll
                for (int f = 0; f < 4; ++f) {
                    int col = wc + f * 16 + lr;
                    float bv = bo[col];
                    #pragma unroll
                    for (int rr = 0; rr < 4; ++rr) {
                        int row = r0 + wr + lg * 4 + rr;
                        x1[f][rr] = acc[f][rr] + bv + bf2f(xg[(size_t)row * 256 + col]);
                    }
                }
                need_store = true;
            } else if (p == 1) {
                #pragma unroll
                for (int f = 0; f < 4; ++f) {
                    int col = wc + f * 16 + lr;
                    float bv = bmlp[col];
                    #pragma unroll
                    for (int rr = 0; rr < 4; ++rr) {
                        int row = r0 + wr + lg * 4 + rr;
                        float v = x1[f][rr] + acc[f][rr] + bv;
                        x2[f][rr] = v;
                        xg[(size_t)row * 256 + col] = f2bf(v);
                    }
                }
                need_store = !last;
            } else {
                int nc = p - 2;
                #pragma unroll
                for (int f = 0; f < 4; ++f) {
                    int col = wc + f * 16 + lr;
                    float bv = bqkv[nc * 256 + col];
                    int h2 = col >> 6, d = col & 63;
                    int bh = b * 4 + h2;
                    int t2 = (r0 & 2047) + wr + lg * 4;
                    if (nc == 2) {
                        short4_t pk;
                        #pragma unroll
                        for (int rr = 0; rr < 4; ++rr) pk[rr] = f2bf(acc[f][rr] + bv);
                        *(short4_t*)&vg[(size_t)bh * 131072 + (size_t)d * 2048 + t2] = pk;
                    } else {
                        short* dst = (nc == 0 ? qg : kg) + (size_t)bh * 131072 + (size_t)t2 * 64 + d;
                        #pragma unroll
                        for (int rr = 0; rr < 4; ++rr) dst[rr * 64] = f2bf(acc[f][rr] + bv);
                    }
                }
            }
            #pragma unroll
            for (int f = 0; f < 4; ++f) acc[f] = (f32x4){0.f, 0.f, 0.f, 0.f};
        }
        __builtin_amdgcn_s_barrier();        // all waves done with wl[s&1] and al
        if (s + 2 < nsteps) stage_w(s + 2);  // overlaps al store + barrier below
        if (need_store) {
            store_a(p == 0 ? x1 : x2);
            asm volatile("s_waitcnt lgkmcnt(0)" ::: "memory");
            __builtin_amdgcn_s_barrier();
        }
    }
}

// ---------------------------------------------------------------------------
extern "C" void kernel_launch(void* const* d_in, const int* in_sizes, int n_in,
                              void* d_out, int out_size, void* d_ws, size_t ws_size,
                              hipStream_t stream) {
    (void)in_sizes; (void)n_in; (void)out_size; (void)ws_size;
    const int*   idx   = (const int*)  d_in[0];
    const float* tok   = (const float*)d_in[1];
    const float* pos   = (const float*)d_in[2];
    const float* Wqkv  = (const float*)d_in[3];
    const float* bqkv  = (const float*)d_in[4];
    const float* Wo    = (const float*)d_in[5];
    const float* bo    = (const float*)d_in[6];
    const float* Wfc   = (const float*)d_in[7];
    const float* bfc   = (const float*)d_in[8];
    const float* Wfp   = (const float*)d_in[9];
    const float* bfp   = (const float*)d_in[10];
    const float* Whead = (const float*)d_in[11];

    float* out = (float*)d_out;                   // logits only
    float* ws  = (float*)d_ws;                    // all scratch (>=268 MB)

    short* xg      = (short*)ws;                  // [8192][256] bf16 residual
    short* Opb     = (short*)(ws + 2097152);      // [4096 slabs][4096] bf16
    float* rspart  = ws + 10485760;               // [4096 slabs][64] fp32
    short* wqkv_t  = (short*)(ws + 10747904);     // [4][768][256]
    short* wo_t    = wqkv_t + 786432;             // [4][256][256]
    short* wmlp_t  = wo_t + 262144;               // [4][256][256]
    short* whead_t = wmlp_t + 262144;             // [2048][256]
    float* bmlp    = (float*)(whead_t + 524288);  // [4][256]
    float* bq_s    = bmlp + 1024;                 // [4][768]
    short* qgp     = (short*)(bq_s + 3072);       // [16][2048][64]
    short* kgp     = qgp + 2097152;
    short* vgp     = kgp + 2097152;               // [16][64][2048]
    float* wmlp_part = ws + 40000000;             // [256 slabs][4096] fp32
    float* bmlp_part = ws + 41048576;             // [64][256] fp32

    prep_kernel<<<3908, 256, 0, stream>>>(
        Wqkv, Wo, Wfc, Wfp, Whead, bfc, bqkv, idx, tok, pos,
        wqkv_t, wo_t, whead_t, wmlp_part, bmlp_part, bq_s, xg);
    // qkv for layer 0 + piggybacked Wmlp/bmlp combine (blockIdx.y >= 128)
    gemmb_kernel<1><<<dim3(12, 134), 256, 0, stream>>>(
        xg, wqkv_t, bq_s, nullptr, qgp, kgp, vgp,
        wmlp_part, bmlp_part, bfp, wmlp_t, bmlp, 768, 256);

    for (int l = 0; l < 4; ++l) {
        attn_kernel<<<2304, 256, 0, stream>>>(qgp, kgp, vgp, Opb, rspart);
        bool last = (l == 3);
        layer_kernel<<<256, 512, 0, stream>>>(
            Opb, rspart, xg,
            wo_t + l * 65536, bo + l * 256,
            wmlp_t + l * 65536, bmlp + l * 256,
            last ? nullptr : (wqkv_t + (l + 1) * 196608),
            last ? nullptr : (bq_s + (l + 1) * 768),
            last ? nullptr : qgp, last ? nullptr : kgp, last ? nullptr : vgp);
    }
    // head: logits = xg @ whead_t^T (bf16 pipeline, coalesced fp32 out)
    gemmb_kernel<0><<<dim3(32, 128), 256, 0, stream>>>(
        xg, whead_t, nullptr, out, nullptr, nullptr, nullptr,
        nullptr, nullptr, nullptr, nullptr, nullptr, 2048, 256);
}

// Round 23
// 207.296 us; speedup vs baseline: 1.0099x; 1.0099x over previous
//
#include <hip/hip_runtime.h>

// GPT forward, MI355X gfx950. bf16 MFMA, fused MLP (no activation), max-free
// exp2-softmax (Q pre-scaled log2(e)/8 in weights), KV-split (4-tile chunks)
// XCD-pinned attn @4 blocks/CU, bf16 O-partials, bf16 residual stream,
// fused layer megakernel, bf16 head GEMM with LDS-transposed coalesced
// epilogue. All scratch in d_ws. B=4,T=2048,C=256,H=4,D=64,L=4.
// (Round-21 configuration: best measured, 208.2 us.)

typedef __attribute__((ext_vector_type(8))) short short8;
typedef __attribute__((ext_vector_type(4))) short short4_t;
typedef __attribute__((ext_vector_type(4))) float f32x4;

#define QSCALE 0.18033688011112042f   // log2(e)/8 : softmax computed as exp2

static __device__ __forceinline__ short f2bf(float f) {
    unsigned int u = __float_as_uint(f);
    unsigned int r = (u + 0x7FFFu + ((u >> 16) & 1u)) >> 16;  // RNE
    return (short)r;
}
static __device__ __forceinline__ float bf2f(short s) {
    return __uint_as_float(((unsigned)(unsigned short)s) << 16);
}

static __device__ __forceinline__ void glds16(const void* g, void* l) {
    __builtin_amdgcn_global_load_lds(
        (const __attribute__((address_space(1))) unsigned int*)g,
        (__attribute__((address_space(3))) unsigned int*)l, 16, 0, 0);
}

// ---------------- consolidated prep + embed ----------------------------------
__global__ __launch_bounds__(256) void prep_kernel(
    const float* __restrict__ Wqkv, const float* __restrict__ Wo,
    const float* __restrict__ Wfc, const float* __restrict__ Wfp,
    const float* __restrict__ Whead, const float* __restrict__ bfc,
    const float* __restrict__ bqkv,
    const int* __restrict__ idx, const float* __restrict__ tok,
    const float* __restrict__ pos,
    short* __restrict__ wqkv_t, short* __restrict__ wo_t,
    short* __restrict__ whead_t,
    float* __restrict__ wmlp_part, float* __restrict__ bmlp_part,
    float* __restrict__ bq_s, short* __restrict__ xb) {
    int b = blockIdx.x;
    if (b >= 1860) {
        int i = ((b - 1860) * 256 + threadIdx.x) * 4;
        int row = i >> 8, c = i & 255, t = row & 2047;
        int tr = idx[row];
        float4 a = *(const float4*)(tok + (size_t)tr * 256 + c);
        float4 p = *(const float4*)(pos + (size_t)t * 256 + c);
        short4_t s;
        s.x = f2bf(a.x + p.x); s.y = f2bf(a.y + p.y);
        s.z = f2bf(a.z + p.z); s.w = f2bf(a.w + p.w);
        *(short4_t*)(xb + i) = s;
        return;
    }
    if (b < 1536) {
        __shared__ float tile[32][33];
        const float* src; short* dst; int R, C, c0, r0; bool qs = false;
        if (b < 768)       { int l = b / 192, r = b % 192;
            src = Wqkv + (size_t)l * 196608; dst = wqkv_t + (size_t)l * 196608;
            R = 256; C = 768; c0 = (r % 24) * 32; r0 = (r / 24) * 32; qs = true; }
        else if (b < 1024) { int t = b - 768; int l = t >> 6, r = t & 63;
            src = Wo + (size_t)l * 65536; dst = wo_t + (size_t)l * 65536;
            R = 256; C = 256; c0 = (r & 7) * 32; r0 = (r >> 3) * 32; }
        else               { int t = b - 1024;
            src = Whead; dst = whead_t;
            R = 256; C = 2048; c0 = (t & 63) * 32; r0 = (t >> 6) * 32; }
        int tx = threadIdx.x & 31, ty = threadIdx.x >> 5;
        #pragma unroll
        for (int i = 0; i < 4; ++i)
            tile[ty + 8 * i][tx] = src[(size_t)(r0 + ty + 8 * i) * C + c0 + tx];
        __syncthreads();
        #pragma unroll
        for (int i = 0; i < 4; ++i) {
            int n = c0 + ty + 8 * i;
            float v = tile[tx][ty + 8 * i];
            if (qs && n < 256) v *= QSCALE;
            dst[(size_t)n * R + r0 + tx] = f2bf(v);
        }
    } else if (b < 1792) {
        __shared__ short As[2][64][40];
        __shared__ short Bs[2][64][40];
        int t = b - 1536, l = t >> 6, r = (t >> 2) & 15, kc = t & 3;
        const float* A = Wfc + (size_t)l * 262144;
        const float* W = Wfp + (size_t)l * 262144;
        int m0 = (r >> 2) * 64, n0 = (r & 3) * 64, kb = kc * 256;
        int tid = threadIdx.x, lane = tid & 63, wid = tid >> 6;
        int lg = lane >> 4, lr = lane & 15;
        int wm = (wid >> 1) * 32, wn = (wid & 1) * 32;
        f32x4 acc[2][2] = {};
        float4 pa0, pa1; float pb[8];
        int ar = tid >> 3, ac4 = (tid & 7) * 4;
        int bn = tid & 63, bk8 = (tid >> 6) * 8;
        auto gload = [&](int k0) {
            pa0 = *(const float4*)(A + (size_t)(m0 + ar) * 1024 + k0 + ac4);
            pa1 = *(const float4*)(A + (size_t)(m0 + ar + 32) * 1024 + k0 + ac4);
            #pragma unroll
            for (int j = 0; j < 8; ++j) pb[j] = W[(size_t)(k0 + bk8 + j) * 256 + n0 + bn];
        };
        auto sstore = [&](int buf) {
            short4_t s0; s0.x=f2bf(pa0.x); s0.y=f2bf(pa0.y); s0.z=f2bf(pa0.z); s0.w=f2bf(pa0.w);
            *(short4_t*)&As[buf][ar][ac4] = s0;
            short4_t s1; s1.x=f2bf(pa1.x); s1.y=f2bf(pa1.y); s1.z=f2bf(pa1.z); s1.w=f2bf(pa1.w);
            *(short4_t*)&As[buf][ar + 32][ac4] = s1;
            short8 bb;
            #pragma unroll
            for (int j = 0; j < 8; ++j) bb[j] = f2bf(pb[j]);
            *(short8*)&Bs[buf][bn][bk8] = bb;
        };
        gload(kb); sstore(0); __syncthreads();
        for (int tt = 0; tt < 8; ++tt) {
            if (tt + 1 < 8) gload(kb + ((tt + 1) << 5));
            int cur = tt & 1;
            short8 af[2], bfr[2];
            af[0]  = *(const short8*)&As[cur][wm + lr][lg * 8];
            af[1]  = *(const short8*)&As[cur][wm + 16 + lr][lg * 8];
            bfr[0] = *(const short8*)&Bs[cur][wn + lr][lg * 8];
            bfr[1] = *(const short8*)&Bs[cur][wn + 16 + lr][lg * 8];
            #pragma unroll
            for (int mi = 0; mi < 2; ++mi)
                #pragma unroll
                for (int ni = 0; ni < 2; ++ni)
                    acc[mi][ni] = __builtin_amdgcn_mfma_f32_16x16x32_bf16(
                        af[mi], bfr[ni], acc[mi][ni], 0, 0, 0);
            if (tt + 1 < 8) sstore((tt + 1) & 1);
            __syncthreads();
        }
        float* part = wmlp_part + (size_t)t * 4096;
        #pragma unroll
        for (int mi = 0; mi < 2; ++mi)
            #pragma unroll
            for (int ni = 0; ni < 2; ++ni) {
                int col = wn + ni * 16 + lr;
                #pragma unroll
                for (int rr = 0; rr < 4; ++rr) {
                    int row = wm + mi * 16 + lg * 4 + rr;
                    part[row * 64 + col] = acc[mi][ni][rr];
                }
            }
    } else if (b < 1856) {
        int t = b - 1792, l = t >> 4, kc = t & 15;
        int n = threadIdx.x;
        const float* w = Wfp + (size_t)l * 262144 + n;
        const float* bf = bfc + l * 1024;
        float s = 0.0f;
        #pragma unroll 8
        for (int k = kc * 64; k < kc * 64 + 64; ++k)
            s += bf[k] * w[(size_t)k * 256];
        bmlp_part[t * 256 + n] = s;
    } else {
        int l = b - 1856;
        for (int k = threadIdx.x; k < 768; k += 256)
            bq_s[l * 768 + k] = bqkv[l * 768 + k] * (k < 256 ? QSCALE : 1.0f);
    }
}

// ---------------- bf16 GEMM core (3-buf glds pipeline) -----------------------
// MODE 0: fp32 out via LDS-transposed coalesced epilogue (head).
// MODE 1: qkv split epilogue + piggybacked combine at blockIdx.y >= 128.
template<int MODE>
__global__ __launch_bounds__(256) void gemmb_kernel(
    const short* __restrict__ A, const short* __restrict__ Bt,
    const float* __restrict__ bias, float* __restrict__ outf,
    short* __restrict__ qg, short* __restrict__ kg, short* __restrict__ vg,
    const float* __restrict__ wmlp_part, const float* __restrict__ bmlp_part,
    const float* __restrict__ bfp,
    short* __restrict__ wmlp_t, float* __restrict__ bmlp,
    int N, int K) {
    if constexpr (MODE == 1) {
        if (blockIdx.y >= 128) {          // piggybacked combine blocks
            int t = (blockIdx.y - 128) * 12 + blockIdx.x;
            if (t >= 68) return;
            if (t < 64) {
                int l = t >> 4, r = t & 15;
                int m0 = (r >> 2) * 64, n0 = (r & 3) * 64;
                int slab0 = t * 4;
                int rc = threadIdx.x >> 6, nl = threadIdx.x & 63;
                #pragma unroll
                for (int rr = 0; rr < 16; ++rr) {
                    int row = rc * 16 + rr;
                    float s = wmlp_part[(size_t)(slab0 + 0) * 4096 + row * 64 + nl]
                            + wmlp_part[(size_t)(slab0 + 1) * 4096 + row * 64 + nl]
                            + wmlp_part[(size_t)(slab0 + 2) * 4096 + row * 64 + nl]
                            + wmlp_part[(size_t)(slab0 + 3) * 4096 + row * 64 + nl];
                    wmlp_t[(size_t)l * 65536 + (size_t)(n0 + nl) * 256 + m0 + row] = f2bf(s);
                }
            } else {
                int l = t - 64, n = threadIdx.x;
                float s = bfp[l * 256 + n];
                #pragma unroll
                for (int kc = 0; kc < 16; ++kc)
                    s += bmlp_part[(l * 16 + kc) * 256 + n];
                bmlp[l * 256 + n] = s;
            }
            return;
        }
    }
    __shared__ short Asb[3][4096];
    __shared__ short Bsb[3][4096];
    int tid = threadIdx.x, lane = tid & 63, wid = tid >> 6;
    int lg = lane >> 4, lr = lane & 15;
    int m0 = blockIdx.y * 64, n0 = blockIdx.x * 64;
    int wm = (wid >> 1) * 32, wn = (wid & 1) * 32;
    int srow = lane >> 3;
    int gc = (lane & 7) ^ (srow & 7);
    int nt = K >> 6;

    auto stage = [&](int t) {
        int buf = t - (t / 3) * 3;
        int k0 = t << 6;
        #pragma unroll
        for (int o2 = 0; o2 < 2; ++o2) {
            int o = wid * 2 + o2;
            glds16(A + (size_t)(m0 + o * 8 + srow) * K + k0 + gc * 8, &Asb[buf][o * 512]);
            glds16(Bt + (size_t)(n0 + o * 8 + srow) * K + k0 + gc * 8, &Bsb[buf][o * 512]);
        }
    };

    f32x4 acc[2][2] = {};
    stage(0);
    if (nt > 1) stage(1);

    for (int t = 0; t < nt; ++t) {
        if (t + 1 < nt) asm volatile("s_waitcnt vmcnt(4)" ::: "memory");
        else            asm volatile("s_waitcnt vmcnt(0)" ::: "memory");
        __builtin_amdgcn_s_barrier();
        if (t + 2 < nt) stage(t + 2);
        int buf = t - (t / 3) * 3;
        short8 af[2][2], bfr[2][2];
        #pragma unroll
        for (int mi = 0; mi < 2; ++mi) {
            int row = wm + mi * 16 + lr;
            #pragma unroll
            for (int h = 0; h < 2; ++h)
                af[mi][h] = *(const short8*)&Asb[buf][row * 64 + ((h * 4 + lg) ^ (lr & 7)) * 8];
        }
        #pragma unroll
        for (int ni = 0; ni < 2; ++ni) {
            int row = wn + ni * 16 + lr;
            #pragma unroll
            for (int h = 0; h < 2; ++h)
                bfr[ni][h] = *(const short8*)&Bsb[buf][row * 64 + ((h * 4 + lg) ^ (lr & 7)) * 8];
        }
        #pragma unroll
        for (int h = 0; h < 2; ++h)
            #pragma unroll
            for (int mi = 0; mi < 2; ++mi)
                #pragma unroll
                for (int ni = 0; ni < 2; ++ni)
                    acc[mi][ni] = __builtin_amdgcn_mfma_f32_16x16x32_bf16(
                        af[mi][h], bfr[ni][h], acc[mi][ni], 0, 0, 0);
    }

    if constexpr (MODE == 0) {
        // LDS-transposed epilogue: coalesced 256B row segments.
        __syncthreads();                       // staging buffers now dead
        float* ot = (float*)&Asb[0][0];        // 24 KB >= 64*68*4 B
        #pragma unroll
        for (int mi = 0; mi < 2; ++mi)
            #pragma unroll
            for (int ni = 0; ni < 2; ++ni)
                #pragma unroll
                for (int r = 0; r < 4; ++r)
                    ot[(wm + mi * 16 + lg * 4 + r) * 68 + wn + ni * 16 + lr]
                        = acc[mi][ni][r];
        __syncthreads();
        #pragma unroll
        for (int pass = 0; pass < 4; ++pass) {
            int row = pass * 16 + (tid >> 4);
            int col = (tid & 15) * 4;
            f32x4 v = *(const f32x4*)&ot[row * 68 + col];
            __builtin_nontemporal_store(v,
                (f32x4*)&outf[(size_t)(m0 + row) * N + n0 + col]);
        }
    } else {
        #pragma unroll
        for (int mi = 0; mi < 2; ++mi) {
            #pragma unroll
            for (int ni = 0; ni < 2; ++ni) {
                int col = n0 + wn + ni * 16 + lr;
                float bv = bias[col];
                int sec = col >> 8, h = (col >> 6) & 3, d = col & 63;
                int rb = m0 + wm + mi * 16 + lg * 4;
                int t2 = rb & 2047, bh = ((rb >> 11) << 2) | h;
                if (sec == 2) {
                    short4_t pk;
                    #pragma unroll
                    for (int r = 0; r < 4; ++r) pk[r] = f2bf(acc[mi][ni][r] + bv);
                    *(short4_t*)&vg[(size_t)bh * 131072 + (size_t)d * 2048 + t2] = pk;
                } else {
                    short* dst = (sec == 0 ? qg : kg) + (size_t)bh * 131072 + (size_t)t2 * 64 + d;
                    #pragma unroll
                    for (int r = 0; r < 4; ++r) dst[r * 64] = f2bf(acc[mi][ni][r] + bv);
                }
            }
        }
    }
}

// ---------------- causal flash attention, 4-tile chunks, XCD-pinned ----------
// Ps unpadded [4][16][64] with chunk-XOR swizzle -> 40960 B LDS -> 4 blocks/CU.
__global__ __launch_bounds__(256, 4) void attn_kernel(
    const short* __restrict__ qg, const short* __restrict__ kg,
    const short* __restrict__ vg, short* __restrict__ Opb, float* __restrict__ rp) {
    __shared__ short Kb[2][4096];
    __shared__ short Vb[2][4096];
    __shared__ short Ps[4][16][64];
    int g = blockIdx.x;
    int idx = g >> 3;
    int bh = (g & 7) * 2 + (idx / 144);
    int i = 143 - (idx % 144);          // heavy chunks first
    int g4 = 0;
    #pragma unroll
    for (int t = 7; t >= 1; --t) if (i >= 2 * t * (t + 1)) { g4 = t; break; }
    int j0 = i - 2 * g4 * (g4 + 1);
    int qq = j0 / (g4 + 1);
    int qt = g4 * 4 + qq;
    int s = j0 - qq * (g4 + 1);
    int t0 = s * 4;
    int t1 = min(t0 + 4, qt + 1);
    int q0 = qt << 6;
    int tid = threadIdx.x, lane = tid & 63, wid = tid >> 6;
    int lg = lane >> 4, lr = lane & 15;
    const size_t base = (size_t)bh << 17;
    int srow = lane >> 3;
    int gc = (lane & 7) ^ (srow & 7);

    const short* qrow = qg + base + (size_t)(q0 + wid * 16 + lr) * 64;
    short8 qf0 = *(const short8*)(qrow + lg * 8);
    short8 qf1 = *(const short8*)(qrow + 32 + lg * 8);

    auto stage = [&](int t) {
        int buf = (t - t0) & 1;
        #pragma unroll
        for (int o2 = 0; o2 < 2; ++o2) {
            int o = wid * 2 + o2;
            glds16(kg + base + (size_t)(t * 64 + o * 8 + srow) * 64 + gc * 8, &Kb[buf][o * 512]);
            glds16(vg + base + (size_t)(o * 8 + srow) * 2048 + t * 64 + gc * 8, &Vb[buf][o * 512]);
        }
    };

    f32x4 o[4] = {};
    float rs = 0.0f;
    stage(t0);

    for (int j = t0; j < t1; ++j) {
        if (j + 1 < t1) {
            stage(j + 1);
            asm volatile("s_waitcnt vmcnt(4)" ::: "memory");
        } else {
            asm volatile("s_waitcnt vmcnt(0)" ::: "memory");
        }
        __builtin_amdgcn_s_barrier();
        int buf = (j - t0) & 1;

        f32x4 sv[4];
        #pragma unroll
        for (int nf = 0; nf < 4; ++nf) {
            int row = nf * 16 + lr;
            short8 k0f = *(const short8*)&Kb[buf][row * 64 + ((0 + lg) ^ (lr & 7)) * 8];
            short8 k1f = *(const short8*)&Kb[buf][row * 64 + ((4 + lg) ^ (lr & 7)) * 8];
            f32x4 z = {};
            z = __builtin_amdgcn_mfma_f32_16x16x32_bf16(k0f, qf0, z, 0, 0, 0);
            z = __builtin_amdgcn_mfma_f32_16x16x32_bf16(k1f, qf1, z, 0, 0, 0);
            sv[nf] = z;
        }
        bool diagt = (j == qt);
        #pragma unroll
        for (int nf = 0; nf < 4; ++nf) {
            float pe[4];
            if (diagt) {
                #pragma unroll
                for (int r = 0; r < 4; ++r) {
                    float v = sv[nf][r];
                    if (nf * 16 + lg * 4 + r > wid * 16 + lr) v = -3e38f;
                    asm("v_exp_f32 %0, %1" : "=v"(pe[r]) : "v"(v));
                }
            } else {
                #pragma unroll
                for (int r = 0; r < 4; ++r)
                    asm("v_exp_f32 %0, %1" : "=v"(pe[r]) : "v"(sv[nf][r]));
            }
            rs += (pe[0] + pe[1]) + (pe[2] + pe[3]);
            unsigned r01, r23;
            asm("v_cvt_pk_bf16_f32 %0, %1, %2" : "=v"(r01) : "v"(pe[0]), "v"(pe[1]));
            asm("v_cvt_pk_bf16_f32 %0, %1, %2" : "=v"(r23) : "v"(pe[2]), "v"(pe[3]));
            uint2 u2; u2.x = r01; u2.y = r23;
            *(uint2*)&Ps[wid][lr][((nf * 2 + (lg >> 1)) ^ (lr & 7)) * 8 + (lg & 1) * 4] = u2;
        }
        short8 pf0 = *(const short8*)&Ps[wid][lr][((lg) ^ (lr & 7)) * 8];
        short8 pf1 = *(const short8*)&Ps[wid][lr][((4 + lg) ^ (lr & 7)) * 8];
        #pragma unroll
        for (int df = 0; df < 4; ++df) {
            int row = df * 16 + lr;
            short8 v0 = *(const short8*)&Vb[buf][row * 64 + ((0 + lg) ^ (lr & 7)) * 8];
            short8 v1 = *(const short8*)&Vb[buf][row * 64 + ((4 + lg) ^ (lr & 7)) * 8];
            o[df] = __builtin_amdgcn_mfma_f32_16x16x32_bf16(pf0, v0, o[df], 0, 0, 0);
            o[df] = __builtin_amdgcn_mfma_f32_16x16x32_bf16(pf1, v1, o[df], 0, 0, 0);
        }
        __builtin_amdgcn_s_barrier();
    }

    rs += __shfl_xor(rs, 16);
    rs += __shfl_xor(rs, 32);

    int slab = ((bh * 32 + qt) << 3) + s;
    short* ob = Opb + (size_t)slab * 4096;
    #pragma unroll
    for (int df = 0; df < 4; ++df)
        #pragma unroll
        for (int r = 0; r < 4; ++r)
            __builtin_nontemporal_store(f2bf(o[df][r]),
                ob + (wid * 16 + lg * 4 + r) * 64 + df * 16 + lr);
    if (lane < 16) rp[slab * 64 + wid * 16 + lane] = rs;
}

// ---------------- fused layer: combine+proj+MLP+next-qkv ---------------------
// bf16 residual stream xg (read p0, written p1; last layer's write = head A).
// XCD-pinned: block bid -> xcd=bid&7 serves batch b=xcd>>1 (matches attn pin).
__global__ __launch_bounds__(512) void layer_kernel(
    const short* __restrict__ Opb, const float* __restrict__ rp,
    short* __restrict__ xg,
    const short* __restrict__ wo, const float* __restrict__ bo,
    const short* __restrict__ wmlp, const float* __restrict__ bmlp,
    const short* __restrict__ wqkv, const float* __restrict__ bqkv,
    short* __restrict__ qg, short* __restrict__ kg, short* __restrict__ vg) {
    __shared__ short al[4][32][64];      // 16 KB (A operand, swizzled)
    __shared__ short wl[2][32768];       // 2 x 64 KB (weight half-K buffers)
    int tid = threadIdx.x, lane = tid & 63, wid = tid >> 6;
    int lg = (lane >> 4) & 3, lr = lane & 15;
    int bid = blockIdx.x;
    int xcd = bid & 7, slot = bid >> 3;
    int b = xcd >> 1;
    int r0 = (b * 64 + slot * 2 + (xcd & 1)) * 32;
    int qt = (r0 & 2047) >> 6;
    int rowIn0 = r0 & 32;
    int ns = (qt >> 2) + 1;
    int wr = (wid & 1) * 16, wc = (wid >> 1) * 64;
    bool last = (wqkv == nullptr);

    const short* wlist[5];
    wlist[0] = wo; wlist[1] = wmlp;
    wlist[2] = last ? wo : wqkv;
    wlist[3] = last ? wo : wqkv + 65536;
    wlist[4] = last ? wo : wqkv + 131072;
    int nsteps = last ? 4 : 10;

    // ---- combine bf16 partials -> y bf16 in al ----
    {
        int row = tid >> 4, seg = tid & 15;
        int h = seg >> 2, d0 = (seg & 3) * 16;
        int slab0 = (((b * 4 + h) * 32 + qt) << 3);
        float a[16] = {};
        float rtot = 0.0f;
        for (int s = 0; s < ns; ++s) {
            const short* op = Opb + (size_t)(slab0 + s) * 4096 + (rowIn0 + row) * 64 + d0;
            #pragma unroll
            for (int i2 = 0; i2 < 4; ++i2) {
                short4_t v = *(const short4_t*)(op + i2 * 4);
                a[i2*4+0] += bf2f(v.x); a[i2*4+1] += bf2f(v.y);
                a[i2*4+2] += bf2f(v.z); a[i2*4+3] += bf2f(v.w);
            }
            rtot += rp[(slab0 + s) * 64 + rowIn0 + row];
        }
        float inv = 1.0f / rtot;
        short8 o0, o1;
        #pragma unroll
        for (int i2 = 0; i2 < 8; ++i2) { o0[i2] = f2bf(a[i2] * inv); o1[i2] = f2bf(a[8 + i2] * inv); }
        int c0 = d0 >> 3;
        *(short8*)&al[h][row][((c0) ^ (row & 7)) * 8] = o0;
        *(short8*)&al[h][row][((c0 + 1) ^ (row & 7)) * 8] = o1;
    }

    auto stage_w = [&](int s) {
        const short* wt = wlist[s >> 1];
        int h = s & 1;
        short* dst = wl[h];
        int n_l = lane >> 4, cl = lane & 15;
        #pragma unroll
        for (int c4 = 0; c4 < 8; ++c4) {
            int n0 = wid * 32 + c4 * 4;
            int n = n0 + n_l;
            glds16(wt + (size_t)n * 256 + h * 128 + (cl ^ (n & 15)) * 8,
                   dst + n0 * 128);
        }
    };
    auto store_a = [&](f32x4* v) {
        #pragma unroll
        for (int f = 0; f < 4; ++f) {
            int col = wc + f * 16 + lr;
            int h2 = col >> 6, ch = (col & 63) >> 3, pos = col & 7;
            #pragma unroll
            for (int rr = 0; rr < 4; ++rr) {
                int row = wr + lg * 4 + rr;
                al[h2][row][(ch ^ (row & 7)) * 8 + pos] = f2bf(v[f][rr]);
            }
        }
    };

    stage_w(0);
    stage_w(1);
    asm volatile("s_waitcnt lgkmcnt(0)" ::: "memory");
    __builtin_amdgcn_s_barrier();

    f32x4 acc[4] = {};
    f32x4 x1[4], x2[4];

    for (int s = 0; s < nsteps; ++s) {
        if (s == nsteps - 1) asm volatile("s_waitcnt vmcnt(0)" ::: "memory");
        else                 asm volatile("s_waitcnt vmcnt(8)" ::: "memory");
        __builtin_amdgcn_s_barrier();
        int h = s & 1, p = s >> 1;
        const short* wb = wl[h];
        #pragma unroll
        for (int s2 = 0; s2 < 4; ++s2) {
            int ksg = h * 4 + s2;
            short8 a = *(const short8*)&al[ksg >> 1][wr + lr][((((ksg & 1) << 2) + lg) ^ (lr & 7)) * 8];
            #pragma unroll
            for (int f = 0; f < 4; ++f) {
                int n = wc + f * 16 + lr;
                short8 bf8 = *(const short8*)&wb[n * 128 + (((s2 * 4 + lg) ^ lr) * 8)];
                acc[f] = __builtin_amdgcn_mfma_f32_16x16x32_bf16(a, bf8, acc[f], 0, 0, 0);
            }
        }
        bool phase_end = (h == 1);
        bool need_store = false;
        if (phase_end) {
            if (p == 0) {
                #pragma unroll
                for (int f = 0; f < 4; ++f) {
                    int col = wc + f * 16 + lr;
                    float bv = bo[col];
                    #pragma unroll
                    for (int rr = 0; rr < 4; ++rr) {
                        int row = r0 + wr + lg * 4 + rr;
                        x1[f][rr] = acc[f][rr] + bv + bf2f(xg[(size_t)row * 256 + col]);
                    }
                }
                need_store = true;
            } else if (p == 1) {
                #pragma unroll
                for (int f = 0; f < 4; ++f) {
                    int col = wc + f * 16 + lr;
                    float bv = bmlp[col];
                    #pragma unroll
                    for (int rr = 0; rr < 4; ++rr) {
                        int row = r0 + wr + lg * 4 + rr;
                        float v = x1[f][rr] + acc[f][rr] + bv;
                        x2[f][rr] = v;
                        xg[(size_t)row * 256 + col] = f2bf(v);
                    }
                }
                need_store = !last;
            } else {
                int nc = p - 2;
                #pragma unroll
                for (int f = 0; f < 4; ++f) {
                    int col = wc + f * 16 + lr;
                    float bv = bqkv[nc * 256 + col];
                    int h2 = col >> 6, d = col & 63;
                    int bh = b * 4 + h2;
                    int t2 = (r0 & 2047) + wr + lg * 4;
                    if (nc == 2) {
                        short4_t pk;
                        #pragma unroll
                        for (int rr = 0; rr < 4; ++rr) pk[rr] = f2bf(acc[f][rr] + bv);
                        *(short4_t*)&vg[(size_t)bh * 131072 + (size_t)d * 2048 + t2] = pk;
                    } else {
                        short* dst = (nc == 0 ? qg : kg) + (size_t)bh * 131072 + (size_t)t2 * 64 + d;
                        #pragma unroll
                        for (int rr = 0; rr < 4; ++rr) dst[rr * 64] = f2bf(acc[f][rr] + bv);
                    }
                }
            }
            #pragma unroll
            for (int f = 0; f < 4; ++f) acc[f] = (f32x4){0.f, 0.f, 0.f, 0.f};
        }
        __builtin_amdgcn_s_barrier();
        if (need_store) {
            store_a(p == 0 ? x1 : x2);
            asm volatile("s_waitcnt lgkmcnt(0)" ::: "memory");
            __builtin_amdgcn_s_barrier();
        }
        if (s + 2 < nsteps) stage_w(s + 2);
    }
}

// ---------------------------------------------------------------------------
extern "C" void kernel_launch(void* const* d_in, const int* in_sizes, int n_in,
                              void* d_out, int out_size, void* d_ws, size_t ws_size,
                              hipStream_t stream) {
    (void)in_sizes; (void)n_in; (void)out_size; (void)ws_size;
    const int*   idx   = (const int*)  d_in[0];
    const float* tok   = (const float*)d_in[1];
    const float* pos   = (const float*)d_in[2];
    const float* Wqkv  = (const float*)d_in[3];
    const float* bqkv  = (const float*)d_in[4];
    const float* Wo    = (const float*)d_in[5];
    const float* bo    = (const float*)d_in[6];
    const float* Wfc   = (const float*)d_in[7];
    const float* bfc   = (const float*)d_in[8];
    const float* Wfp   = (const float*)d_in[9];
    const float* bfp   = (const float*)d_in[10];
    const float* Whead = (const float*)d_in[11];

    float* out = (float*)d_out;                   // logits only
    float* ws  = (float*)d_ws;                    // all scratch (>=268 MB)

    short* xg      = (short*)ws;                  // [8192][256] bf16 residual
    short* Opb     = (short*)(ws + 2097152);      // [4096 slabs][4096] bf16
    float* rspart  = ws + 10485760;               // [4096 slabs][64] fp32
    short* wqkv_t  = (short*)(ws + 10747904);     // [4][768][256]
    short* wo_t    = wqkv_t + 786432;             // [4][256][256]
    short* wmlp_t  = wo_t + 262144;               // [4][256][256]
    short* whead_t = wmlp_t + 262144;             // [2048][256]
    float* bmlp    = (float*)(whead_t + 524288);  // [4][256]
    float* bq_s    = bmlp + 1024;                 // [4][768]
    short* qgp     = (short*)(bq_s + 3072);       // [16][2048][64]
    short* kgp     = qgp + 2097152;
    short* vgp     = kgp + 2097152;               // [16][64][2048]
    float* wmlp_part = ws + 40000000;             // [256 slabs][4096] fp32
    float* bmlp_part = ws + 41048576;             // [64][256] fp32

    prep_kernel<<<3908, 256, 0, stream>>>(
        Wqkv, Wo, Wfc, Wfp, Whead, bfc, bqkv, idx, tok, pos,
        wqkv_t, wo_t, whead_t, wmlp_part, bmlp_part, bq_s, xg);
    // qkv for layer 0 + piggybacked Wmlp/bmlp combine (blockIdx.y >= 128)
    gemmb_kernel<1><<<dim3(12, 134), 256, 0, stream>>>(
        xg, wqkv_t, bq_s, nullptr, qgp, kgp, vgp,
        wmlp_part, bmlp_part, bfp, wmlp_t, bmlp, 768, 256);

    for (int l = 0; l < 4; ++l) {
        attn_kernel<<<2304, 256, 0, stream>>>(qgp, kgp, vgp, Opb, rspart);
        bool last = (l == 3);
        layer_kernel<<<256, 512, 0, stream>>>(
            Opb, rspart, xg,
            wo_t + l * 65536, bo + l * 256,
            wmlp_t + l * 65536, bmlp + l * 256,
            last ? nullptr : (wqkv_t + (l + 1) * 196608),
            last ? nullptr : (bq_s + (l + 1) * 768),
            last ? nullptr : qgp, last ? nullptr : kgp, last ? nullptr : vgp);
    }
    // head: logits = xg @ whead_t^T (bf16 pipeline, coalesced fp32 out)
    gemmb_kernel<0><<<dim3(32, 128), 256, 0, stream>>>(
        xg, whead_t, nullptr, out, nullptr, nullptr, nullptr,
        nullptr, nullptr, nullptr, nullptr, nullptr, 2048, 256);
}